// Round 1
// baseline (851.222 us; speedup 1.0000x reference)
//
#include <hip/hip_runtime.h>
#include <hip/hip_bf16.h>
#include <stdint.h>

#define TOKENS 4096
#define IN_F   4096
#define OUT_F  16384

using f32x4  = __attribute__((ext_vector_type(4))) float;
using bf16x8 = __attribute__((ext_vector_type(8))) short;

// round-to-nearest-even f32 -> bf16 (as raw ushort)
static __device__ __forceinline__ ushort f2bf(float f) {
    union { float f; uint32_t u; } v; v.f = f;
    uint32_t u = v.u;
    u += 0x7FFFu + ((u >> 16) & 1u);
    return (ushort)(u >> 16);
}

static __device__ __forceinline__ float tern(float a, float b) {
    float sa = (a > 0.f) ? 1.f : ((a < 0.f) ? -1.f : 0.f);
    float sb = (b > 0.f) ? 1.f : ((b < 0.f) ? -1.f : 0.f);
    return 0.5f * (sa + sb);
}

// ---- preprocessing: ternarize w1,w2 -> bf16 --------------------------------
__global__ __launch_bounds__(256) void k_ternarize(const float4* __restrict__ w1,
                                                   const float4* __restrict__ w2,
                                                   ushort* __restrict__ wb, int n4) {
    int idx = blockIdx.x * blockDim.x + threadIdx.x;
    int stride = gridDim.x * blockDim.x;
    for (int i = idx; i < n4; i += stride) {
        float4 a = w1[i], b = w2[i];
        ushort4 o;
        o.x = f2bf(tern(a.x, b.x));
        o.y = f2bf(tern(a.y, b.y));
        o.z = f2bf(tern(a.z, b.z));
        o.w = f2bf(tern(a.w, b.w));
        reinterpret_cast<ushort4*>(wb)[i] = o;
    }
}

// ---- preprocessing: x f32 -> bf16 ------------------------------------------
__global__ __launch_bounds__(256) void k_xconv(const float4* __restrict__ x,
                                               ushort* __restrict__ xb, int n4) {
    int idx = blockIdx.x * blockDim.x + threadIdx.x;
    int stride = gridDim.x * blockDim.x;
    for (int i = idx; i < n4; i += stride) {
        float4 a = x[i];
        ushort4 o;
        o.x = f2bf(a.x); o.y = f2bf(a.y); o.z = f2bf(a.z); o.w = f2bf(a.w);
        reinterpret_cast<ushort4*>(xb)[i] = o;
    }
}

// ---- main GEMM: C[M,N] = A[M,K](bf16) * B[N,K](bf16)^T + bias --------------
// 128x128 tile, BK=32, 256 threads (4 waves, 2x2), each wave 64x64 via 4x4
// mfma_f32_16x16x32_bf16 fragments. global_load_lds dwordx4 staging.
#define GLOAD_LDS(gp, lp) __builtin_amdgcn_global_load_lds(                     \
    (const __attribute__((address_space(1))) uint32_t*)(gp),                    \
    (__attribute__((address_space(3))) uint32_t*)(lp), 16, 0, 0)

__global__ __launch_bounds__(256, 2) void k_gemm(const ushort* __restrict__ A,
                                                 const ushort* __restrict__ B,
                                                 const float* __restrict__ bias,
                                                 float* __restrict__ C) {
    __shared__ __align__(16) ushort lA[128 * 32];
    __shared__ __align__(16) ushort lB[128 * 32];

    const int tid  = threadIdx.x;
    const int lane = tid & 63;
    const int wave = tid >> 6;
    const int wm = wave >> 1;       // 0..1
    const int wn = wave & 1;        // 0..1
    const int mBase = blockIdx.y * 128;
    const int nBase = blockIdx.x * 128;
    const int lr = lane & 15;       // fragment row/col
    const int lk = (lane >> 4) * 8; // fragment k offset

    f32x4 acc[4][4] = {};

    // staging decomposition: thread -> (row = tid>>2 [0..63], seg = tid&3)
    const int sr = tid >> 2;
    const int ss = (tid & 3) * 8;
    const ushort* gA0 = A + (size_t)(mBase + sr) * IN_F + ss;
    const ushort* gA1 = A + (size_t)(mBase + 64 + sr) * IN_F + ss;
    const ushort* gB0 = B + (size_t)(nBase + sr) * IN_F + ss;
    const ushort* gB1 = B + (size_t)(nBase + 64 + sr) * IN_F + ss;

    char* laByte = (char*)lA;   // linear LDS dest: byte offset tid*16 (+4096 for 2nd half)
    char* lbByte = (char*)lB;

    for (int k0 = 0; k0 < IN_F; k0 += 32) {
        GLOAD_LDS(gA0 + k0, laByte + tid * 16);
        GLOAD_LDS(gA1 + k0, laByte + 4096 + tid * 16);
        GLOAD_LDS(gB0 + k0, lbByte + tid * 16);
        GLOAD_LDS(gB1 + k0, lbByte + 4096 + tid * 16);
        __syncthreads();   // compiler emits vmcnt(0) drain before s_barrier

        bf16x8 af[4], bg[4];
#pragma unroll
        for (int i = 0; i < 4; ++i)
            af[i] = *(const bf16x8*)&lA[(wm * 64 + i * 16 + lr) * 32 + lk];
#pragma unroll
        for (int j = 0; j < 4; ++j)
            bg[j] = *(const bf16x8*)&lB[(wn * 64 + j * 16 + lr) * 32 + lk];

#pragma unroll
        for (int i = 0; i < 4; ++i)
#pragma unroll
            for (int j = 0; j < 4; ++j)
                acc[i][j] = __builtin_amdgcn_mfma_f32_16x16x32_bf16(af[i], bg[j], acc[i][j], 0, 0, 0);

        __syncthreads();   // protect LDS from next iteration's staging
    }

    // epilogue: C/D layout col = lane&15, row = (lane>>4)*4 + reg
#pragma unroll
    for (int i = 0; i < 4; ++i) {
        const int row = mBase + wm * 64 + i * 16 + (lane >> 4) * 4;
#pragma unroll
        for (int j = 0; j < 4; ++j) {
            const int col = nBase + wn * 64 + j * 16 + lr;
            const float bv = bias[col];
#pragma unroll
            for (int q = 0; q < 4; ++q)
                C[(size_t)(row + q) * OUT_F + col] = acc[i][j][q] + bv;
        }
    }
}

// ---- fallback (only if ws too small): fused fp32 tiled GEMM ----------------
__global__ __launch_bounds__(256) void k_fallback(const float* __restrict__ x,
                                                  const float* __restrict__ w1,
                                                  const float* __restrict__ w2,
                                                  const float* __restrict__ bias,
                                                  float* __restrict__ C) {
    __shared__ float sx[64][17];
    __shared__ float sw[64][17];
    const int tid = threadIdx.x;
    const int mb = blockIdx.y * 64, nb = blockIdx.x * 64;
    const int ty = tid >> 4, tx = tid & 15;
    float acc[4][4] = {};
    const int r = tid >> 2, s = (tid & 3) * 4;
    for (int k0 = 0; k0 < IN_F; k0 += 16) {
        float4 xv = *(const float4*)&x[(size_t)(mb + r) * IN_F + k0 + s];
        float4 a1 = *(const float4*)&w1[(size_t)(nb + r) * IN_F + k0 + s];
        float4 a2 = *(const float4*)&w2[(size_t)(nb + r) * IN_F + k0 + s];
        sx[r][s + 0] = xv.x; sx[r][s + 1] = xv.y; sx[r][s + 2] = xv.z; sx[r][s + 3] = xv.w;
        sw[r][s + 0] = tern(a1.x, a2.x); sw[r][s + 1] = tern(a1.y, a2.y);
        sw[r][s + 2] = tern(a1.z, a2.z); sw[r][s + 3] = tern(a1.w, a2.w);
        __syncthreads();
#pragma unroll
        for (int kk = 0; kk < 16; ++kk) {
            float av[4], bv[4];
#pragma unroll
            for (int i = 0; i < 4; ++i) av[i] = sx[ty * 4 + i][kk];
#pragma unroll
            for (int j = 0; j < 4; ++j) bv[j] = sw[tx * 4 + j][kk];
#pragma unroll
            for (int i = 0; i < 4; ++i)
#pragma unroll
                for (int j = 0; j < 4; ++j) acc[i][j] += av[i] * bv[j];
        }
        __syncthreads();
    }
#pragma unroll
    for (int i = 0; i < 4; ++i)
#pragma unroll
        for (int j = 0; j < 4; ++j)
            C[(size_t)(mb + ty * 4 + i) * OUT_F + nb + tx * 4 + j] = acc[i][j] + bias[nb + tx * 4 + j];
}

extern "C" void kernel_launch(void* const* d_in, const int* in_sizes, int n_in,
                              void* d_out, int out_size, void* d_ws, size_t ws_size,
                              hipStream_t stream) {
    const float* x    = (const float*)d_in[0];
    const float* w1   = (const float*)d_in[1];
    const float* w2   = (const float*)d_in[2];
    const float* bias = (const float*)d_in[3];
    float* out = (float*)d_out;

    const size_t need = ((size_t)TOKENS * IN_F + (size_t)OUT_F * IN_F) * sizeof(ushort);
    if (ws_size >= need) {
        ushort* xb = (ushort*)d_ws;
        ushort* wb = xb + (size_t)TOKENS * IN_F;
        k_xconv<<<1024, 256, 0, stream>>>((const float4*)x, xb, TOKENS * IN_F / 4);
        k_ternarize<<<2048, 256, 0, stream>>>((const float4*)w1, (const float4*)w2, wb,
                                              OUT_F * IN_F / 4);
        dim3 grid(OUT_F / 128, TOKENS / 128);
        k_gemm<<<grid, 256, 0, stream>>>(xb, wb, bias, out);
    } else {
        dim3 grid(OUT_F / 64, TOKENS / 64);
        k_fallback<<<grid, 256, 0, stream>>>(x, w1, w2, bias, out);
    }
}

// Round 2
// 718.659 us; speedup vs baseline: 1.1845x; 1.1845x over previous
//
#include <hip/hip_runtime.h>
#include <hip/hip_bf16.h>
#include <stdint.h>

#define TOKENS 4096
#define IN_F   4096
#define OUT_F  16384
#define NT     (IN_F / 32)   // 128 K-tiles of BK=32

using f32x4  = __attribute__((ext_vector_type(4))) float;
using bf16x8 = __attribute__((ext_vector_type(8))) short;

// round-to-nearest-even f32 -> bf16 (raw ushort)
static __device__ __forceinline__ ushort f2bf(float f) {
    union { float f; uint32_t u; } v; v.f = f;
    uint32_t u = v.u;
    u += 0x7FFFu + ((u >> 16) & 1u);
    return (ushort)(u >> 16);
}

static __device__ __forceinline__ float tern(float a, float b) {
    float sa = (a > 0.f) ? 1.f : ((a < 0.f) ? -1.f : 0.f);
    float sb = (b > 0.f) ? 1.f : ((b < 0.f) ? -1.f : 0.f);
    return 0.5f * (sa + sb);
}

// ---- preprocessing -----------------------------------------------------------
__global__ __launch_bounds__(256) void k_ternarize(const float4* __restrict__ w1,
                                                   const float4* __restrict__ w2,
                                                   ushort* __restrict__ wb, int n4) {
    int idx = blockIdx.x * blockDim.x + threadIdx.x;
    int stride = gridDim.x * blockDim.x;
    for (int i = idx; i < n4; i += stride) {
        float4 a = w1[i], b = w2[i];
        ushort4 o;
        o.x = f2bf(tern(a.x, b.x));
        o.y = f2bf(tern(a.y, b.y));
        o.z = f2bf(tern(a.z, b.z));
        o.w = f2bf(tern(a.w, b.w));
        reinterpret_cast<ushort4*>(wb)[i] = o;
    }
}

__global__ __launch_bounds__(256) void k_xconv(const float4* __restrict__ x,
                                               ushort* __restrict__ xb, int n4) {
    int idx = blockIdx.x * blockDim.x + threadIdx.x;
    int stride = gridDim.x * blockDim.x;
    for (int i = idx; i < n4; i += stride) {
        float4 a = x[i];
        ushort4 o;
        o.x = f2bf(a.x); o.y = f2bf(a.y); o.z = f2bf(a.z); o.w = f2bf(a.w);
        reinterpret_cast<ushort4*>(xb)[i] = o;
    }
}

// ---- helpers -----------------------------------------------------------------
#define GLDS(gp, lp) __builtin_amdgcn_global_load_lds(                          \
    (const __attribute__((address_space(1))) uint32_t*)(gp),                    \
    (__attribute__((address_space(3))) uint32_t*)(lp), 16, 0, 0)

// LDS XOR swizzle: flip byte bits [5:4] with row bits [2:1] (z bits [8:7]).
// Involution; moves whole 16B chunks -> compatible with 16B gload/ds_read.
#define SWZ(z) ((z) ^ ((((z) >> 7) & 3) << 4))

#define BARRIER() do { __asm__ __volatile__("" ::: "memory");                   \
    __builtin_amdgcn_s_barrier();                                               \
    __asm__ __volatile__("" ::: "memory"); } while (0)

#define WAITV(n) __asm__ __volatile__("s_waitcnt vmcnt(" #n ")" ::: "memory")

// ---- main GEMM: 256x256 tile, BK=32, ring-4 LDS, counted vmcnt ---------------
// C[M,N] = A[M,K](bf16) * B[N,K](bf16)^T + bias
__global__ __launch_bounds__(512, 2) void k_gemm256(const ushort* __restrict__ A,
                                                    const ushort* __restrict__ B,
                                                    const float* __restrict__ bias,
                                                    float* __restrict__ C) {
    extern __shared__ __align__(16) char smem[];   // 4 bufs x (A 16KB + B 16KB) = 128KB

    const int tid  = threadIdx.x;
    const int lane = tid & 63;
    const int wave = tid >> 6;
    const int wm = wave >> 2;      // 0..1  (M half)
    const int wn = wave & 3;       // 0..3  (N quarter)
    const int lr = lane & 15;
    const int hk = lane >> 4;      // 0..3

    // XCD-aware swizzle: XCD x owns wgp in [x*128,(x+1)*128) = 8 N-panels x 16 M
    const int bid = blockIdx.x;                 // 0..1023, runs on XCD (bid&7)
    const int wgp = (bid & 7) * 128 + (bid >> 3);
    const int mBase = (wgp & 15) * 256;
    const int nBase = (wgp >> 4) * 256;

    // precomputed swizzled read offsets (bytes within buffer region)
    int zA[8], zB[4];
#pragma unroll
    for (int i = 0; i < 8; ++i) {
        int z = (wm * 128 + i * 16 + lr) * 64 + hk * 16;
        zA[i] = SWZ(z);
    }
#pragma unroll
    for (int j = 0; j < 4; ++j) {
        int z = (wn * 64 + j * 16 + lr) * 64 + hk * 16;
        zB[j] = SWZ(z);
    }

    // staging: thread covers 16B chunks q0,q1 of each 16KB region (linear dest);
    // global source is the INVERSE-swizzled logical position (rule #21)
    const int q0 = tid, q1 = tid + 512;
    auto soff = [](int q) -> size_t {
        int z  = q * 16;
        int zs = SWZ(z);
        return (size_t)(zs >> 6) * IN_F + (size_t)((zs & 63) >> 1);
    };
    const ushort* gA0 = A + (size_t)mBase * IN_F + soff(q0);
    const ushort* gA1 = A + (size_t)mBase * IN_F + soff(q1);
    const ushort* gB0 = B + (size_t)nBase * IN_F + soff(q0);
    const ushort* gB1 = B + (size_t)nBase * IN_F + soff(q1);

    f32x4 acc[8][4] = {};

    // prologue: stage tiles 0,1,2 (12 loads/thread in flight)
#pragma unroll
    for (int t = 0; t < 3; ++t) {
        char* bb = smem + t * 32768;
        GLDS(gA0 + (size_t)t * 32, bb + q0 * 16);
        GLDS(gA1 + (size_t)t * 32, bb + q1 * 16);
        GLDS(gB0 + (size_t)t * 32, bb + 16384 + q0 * 16);
        GLDS(gB1 + (size_t)t * 32, bb + 16384 + q1 * 16);
    }
    WAITV(8);        // tile 0 landed; tiles 1,2 still in flight
    BARRIER();

#pragma unroll 1
    for (int T = 0; T < NT; ++T) {
        char* bufA = smem + (T & 3) * 32768;
        char* bufB = bufA + 16384;
        char* sb   = smem + ((T + 3) & 3) * 32768;  // freed by tile T-1
        const bool st = (T + 3 < NT);

        // ---- phase 0: A-frags 0..3 + all B-frags; stage next A ----
        bf16x8 a0[4], bf[4];
#pragma unroll
        for (int i = 0; i < 4; ++i) a0[i] = *(const bf16x8*)(bufA + zA[i]);
#pragma unroll
        for (int j = 0; j < 4; ++j) bf[j] = *(const bf16x8*)(bufB + zB[j]);
        if (st) {
            GLDS(gA0 + (size_t)(T + 3) * 32, sb + q0 * 16);
            GLDS(gA1 + (size_t)(T + 3) * 32, sb + q1 * 16);
        }
        BARRIER();
        __builtin_amdgcn_s_setprio(1);
#pragma unroll
        for (int i = 0; i < 4; ++i)
#pragma unroll
            for (int j = 0; j < 4; ++j)
                acc[i][j] = __builtin_amdgcn_mfma_f32_16x16x32_bf16(a0[i], bf[j], acc[i][j], 0, 0, 0);
        __builtin_amdgcn_s_setprio(0);
        BARRIER();

        // ---- phase 1: A-frags 4..7; stage next B ----
        bf16x8 a1[4];
#pragma unroll
        for (int i = 0; i < 4; ++i) a1[i] = *(const bf16x8*)(bufA + zA[4 + i]);
        if (st) {
            GLDS(gB0 + (size_t)(T + 3) * 32, sb + 16384 + q0 * 16);
            GLDS(gB1 + (size_t)(T + 3) * 32, sb + 16384 + q1 * 16);
        }
        BARRIER();
        __builtin_amdgcn_s_setprio(1);
#pragma unroll
        for (int i = 0; i < 4; ++i)
#pragma unroll
            for (int j = 0; j < 4; ++j)
                acc[4 + i][j] = __builtin_amdgcn_mfma_f32_16x16x32_bf16(a1[i], bf[j], acc[4 + i][j], 0, 0, 0);
        __builtin_amdgcn_s_setprio(0);
        // tile-boundary counted drain: ensure tile T+1 landed, keep rest in flight
        if (T < NT - 3)       { WAITV(8); }
        else if (T == NT - 3) { WAITV(4); }
        else if (T == NT - 2) { WAITV(0); }
        BARRIER();
    }

    // epilogue: C/D layout col = lane&15, row = (lane>>4)*4 + reg
#pragma unroll
    for (int i = 0; i < 8; ++i) {
        const int row = mBase + wm * 128 + i * 16 + hk * 4;
#pragma unroll
        for (int j = 0; j < 4; ++j) {
            const int col = nBase + wn * 64 + j * 16 + lr;
            const float bv = bias[col];
#pragma unroll
            for (int q = 0; q < 4; ++q)
                C[(size_t)(row + q) * OUT_F + col] = acc[i][j][q] + bv;
        }
    }
}

// ---- round-1 128^2 kernel kept as fallback (static 32KB LDS) -----------------
__global__ __launch_bounds__(256, 2) void k_gemm(const ushort* __restrict__ A,
                                                 const ushort* __restrict__ B,
                                                 const float* __restrict__ bias,
                                                 float* __restrict__ C) {
    __shared__ __align__(16) ushort lA[128 * 32];
    __shared__ __align__(16) ushort lB[128 * 32];
    const int tid  = threadIdx.x;
    const int lane = tid & 63;
    const int wave = tid >> 6;
    const int wm = wave >> 1, wn = wave & 1;
    const int mBase = blockIdx.y * 128, nBase = blockIdx.x * 128;
    const int lr = lane & 15, lk = (lane >> 4) * 8;
    f32x4 acc[4][4] = {};
    const int sr = tid >> 2, ss = (tid & 3) * 8;
    const ushort* gA0 = A + (size_t)(mBase + sr) * IN_F + ss;
    const ushort* gA1 = A + (size_t)(mBase + 64 + sr) * IN_F + ss;
    const ushort* gB0 = B + (size_t)(nBase + sr) * IN_F + ss;
    const ushort* gB1 = B + (size_t)(nBase + 64 + sr) * IN_F + ss;
    char* laByte = (char*)lA;
    char* lbByte = (char*)lB;
    for (int k0 = 0; k0 < IN_F; k0 += 32) {
        GLDS(gA0 + k0, laByte + tid * 16);
        GLDS(gA1 + k0, laByte + 4096 + tid * 16);
        GLDS(gB0 + k0, lbByte + tid * 16);
        GLDS(gB1 + k0, lbByte + 4096 + tid * 16);
        __syncthreads();
        bf16x8 af[4], bg[4];
#pragma unroll
        for (int i = 0; i < 4; ++i) af[i] = *(const bf16x8*)&lA[(wm * 64 + i * 16 + lr) * 32 + lk];
#pragma unroll
        for (int j = 0; j < 4; ++j) bg[j] = *(const bf16x8*)&lB[(wn * 64 + j * 16 + lr) * 32 + lk];
#pragma unroll
        for (int i = 0; i < 4; ++i)
#pragma unroll
            for (int j = 0; j < 4; ++j)
                acc[i][j] = __builtin_amdgcn_mfma_f32_16x16x32_bf16(af[i], bg[j], acc[i][j], 0, 0, 0);
        __syncthreads();
    }
#pragma unroll
    for (int i = 0; i < 4; ++i) {
        const int row = mBase + wm * 64 + i * 16 + (lane >> 4) * 4;
#pragma unroll
        for (int j = 0; j < 4; ++j) {
            const int col = nBase + wn * 64 + j * 16 + lr;
            const float bv = bias[col];
#pragma unroll
            for (int q = 0; q < 4; ++q)
                C[(size_t)(row + q) * OUT_F + col] = acc[i][j][q] + bv;
        }
    }
}

// ---- fp32 fallback if ws too small ------------------------------------------
__global__ __launch_bounds__(256) void k_fallback(const float* __restrict__ x,
                                                  const float* __restrict__ w1,
                                                  const float* __restrict__ w2,
                                                  const float* __restrict__ bias,
                                                  float* __restrict__ C) {
    __shared__ float sx[64][17];
    __shared__ float sw[64][17];
    const int tid = threadIdx.x;
    const int mb = blockIdx.y * 64, nb = blockIdx.x * 64;
    const int ty = tid >> 4, tx = tid & 15;
    float acc[4][4] = {};
    const int r = tid >> 2, s = (tid & 3) * 4;
    for (int k0 = 0; k0 < IN_F; k0 += 16) {
        float4 xv = *(const float4*)&x[(size_t)(mb + r) * IN_F + k0 + s];
        float4 a1 = *(const float4*)&w1[(size_t)(nb + r) * IN_F + k0 + s];
        float4 a2 = *(const float4*)&w2[(size_t)(nb + r) * IN_F + k0 + s];
        sx[r][s + 0] = xv.x; sx[r][s + 1] = xv.y; sx[r][s + 2] = xv.z; sx[r][s + 3] = xv.w;
        sw[r][s + 0] = tern(a1.x, a2.x); sw[r][s + 1] = tern(a1.y, a2.y);
        sw[r][s + 2] = tern(a1.z, a2.z); sw[r][s + 3] = tern(a1.w, a2.w);
        __syncthreads();
#pragma unroll
        for (int kk = 0; kk < 16; ++kk) {
            float av[4], bv[4];
#pragma unroll
            for (int i = 0; i < 4; ++i) av[i] = sx[ty * 4 + i][kk];
#pragma unroll
            for (int j = 0; j < 4; ++j) bv[j] = sw[tx * 4 + j][kk];
#pragma unroll
            for (int i = 0; i < 4; ++i)
#pragma unroll
                for (int j = 0; j < 4; ++j) acc[i][j] += av[i] * bv[j];
        }
        __syncthreads();
    }
#pragma unroll
    for (int i = 0; i < 4; ++i)
#pragma unroll
        for (int j = 0; j < 4; ++j)
            C[(size_t)(mb + ty * 4 + i) * OUT_F + nb + tx * 4 + j] = acc[i][j] + bias[nb + tx * 4 + j];
}

extern "C" void kernel_launch(void* const* d_in, const int* in_sizes, int n_in,
                              void* d_out, int out_size, void* d_ws, size_t ws_size,
                              hipStream_t stream) {
    const float* x    = (const float*)d_in[0];
    const float* w1   = (const float*)d_in[1];
    const float* w2   = (const float*)d_in[2];
    const float* bias = (const float*)d_in[3];
    float* out = (float*)d_out;

    const size_t need = ((size_t)TOKENS * IN_F + (size_t)OUT_F * IN_F) * sizeof(ushort);
    if (ws_size >= need) {
        ushort* xb = (ushort*)d_ws;
        ushort* wb = xb + (size_t)TOKENS * IN_F;
        k_xconv<<<1024, 256, 0, stream>>>((const float4*)x, xb, TOKENS * IN_F / 4);
        k_ternarize<<<2048, 256, 0, stream>>>((const float4*)w1, (const float4*)w2, wb,
                                              OUT_F * IN_F / 4);
        hipError_t e = hipFuncSetAttribute((const void*)k_gemm256,
                                           hipFuncAttributeMaxDynamicSharedMemorySize, 131072);
        if (e == hipSuccess) {
            k_gemm256<<<dim3(1024), 512, 131072, stream>>>(xb, wb, bias, out);
        } else {
            dim3 grid(OUT_F / 128, TOKENS / 128);
            k_gemm<<<grid, 256, 0, stream>>>(xb, wb, bias, out);
        }
    } else {
        dim3 grid(OUT_F / 64, TOKENS / 64);
        k_fallback<<<grid, 256, 0, stream>>>(x, w1, w2, bias, out);
    }
}

// Round 3
// 656.952 us; speedup vs baseline: 1.2957x; 1.0939x over previous
//
#include <hip/hip_runtime.h>
#include <hip/hip_bf16.h>
#include <stdint.h>

#define TOKENS 4096
#define IN_F   4096
#define OUT_F  16384
#define NT     (IN_F / 32)   // 128 K-tiles of BK=32

using f32x4  = __attribute__((ext_vector_type(4))) float;
using bf16x8 = __attribute__((ext_vector_type(8))) short;

// round-to-nearest-even f32 -> bf16 (raw ushort)
static __device__ __forceinline__ ushort f2bf(float f) {
    union { float f; uint32_t u; } v; v.f = f;
    uint32_t u = v.u;
    u += 0x7FFFu + ((u >> 16) & 1u);
    return (ushort)(u >> 16);
}

static __device__ __forceinline__ float tern(float a, float b) {
    float sa = (a > 0.f) ? 1.f : ((a < 0.f) ? -1.f : 0.f);
    float sb = (b > 0.f) ? 1.f : ((b < 0.f) ? -1.f : 0.f);
    return 0.5f * (sa + sb);
}

// ---- preprocessing -----------------------------------------------------------
__global__ __launch_bounds__(256) void k_ternarize(const float4* __restrict__ w1,
                                                   const float4* __restrict__ w2,
                                                   ushort* __restrict__ wb, int n4) {
    int idx = blockIdx.x * blockDim.x + threadIdx.x;
    int stride = gridDim.x * blockDim.x;
    for (int i = idx; i < n4; i += stride) {
        float4 a = w1[i], b = w2[i];
        ushort4 o;
        o.x = f2bf(tern(a.x, b.x));
        o.y = f2bf(tern(a.y, b.y));
        o.z = f2bf(tern(a.z, b.z));
        o.w = f2bf(tern(a.w, b.w));
        reinterpret_cast<ushort4*>(wb)[i] = o;
    }
}

__global__ __launch_bounds__(256) void k_xconv(const float4* __restrict__ x,
                                               ushort* __restrict__ xb, int n4) {
    int idx = blockIdx.x * blockDim.x + threadIdx.x;
    int stride = gridDim.x * blockDim.x;
    for (int i = idx; i < n4; i += stride) {
        float4 a = x[i];
        ushort4 o;
        o.x = f2bf(a.x); o.y = f2bf(a.y); o.z = f2bf(a.z); o.w = f2bf(a.w);
        reinterpret_cast<ushort4*>(xb)[i] = o;
    }
}

// ---- helpers -----------------------------------------------------------------
#define GLDS(gp, lp) __builtin_amdgcn_global_load_lds(                          \
    (const __attribute__((address_space(1))) uint32_t*)(gp),                    \
    (__attribute__((address_space(3))) uint32_t*)(lp), 16, 0, 0)

// LDS XOR swizzle: flip byte bits [5:4] with row bits [2:1] (z bits [8:7]).
// Involution; moves whole 16B chunks -> compatible with 16B gload/ds_read.
#define SWZ(z) ((z) ^ ((((z) >> 7) & 3) << 4))

// clobber-free waits/barriers (m201 template style): the compiler keeps
// tracking its own data deps; we only pin cross-phase motion with
// sched_barrier(0) at the tile-publish point.
#define WAITV(n) __asm__ __volatile__("s_waitcnt vmcnt(" #n ")")
#define BAR()    __builtin_amdgcn_s_barrier()
#define FENCE()  __builtin_amdgcn_sched_barrier(0)

// ---- main GEMM: 256x256 tile, BK=32, static ring-4 LDS, counted vmcnt --------
// C[M,N] = A[M,K](bf16) * B[N,K](bf16)^T + bias
__global__ __launch_bounds__(512, 2) void k_gemm256(const ushort* __restrict__ A,
                                                    const ushort* __restrict__ B,
                                                    const float* __restrict__ bias,
                                                    float* __restrict__ C) {
    extern __shared__ __align__(16) char smem[];   // 4 bufs x (A 16KB + B 16KB) = 128KB

    const int tid  = threadIdx.x;
    const int lane = tid & 63;
    const int wave = tid >> 6;
    const int wm = wave >> 2;      // 0..1  (M half)
    const int wn = wave & 3;       // 0..3  (N quarter)
    const int lr = lane & 15;
    const int hk = lane >> 4;      // 0..3

    // XCD-aware swizzle: XCD x owns wgp in [x*128,(x+1)*128) (1024 % 8 == 0)
    const int bid = blockIdx.x;
    const int wgp = (bid & 7) * 128 + (bid >> 3);
    const int mBase = (wgp & 15) * 256;
    const int nBase = (wgp >> 4) * 256;

    // swizzled ds_read offsets (bytes within buffer region)
    int zA[8], zB[4];
#pragma unroll
    for (int i = 0; i < 8; ++i) {
        int z = (wm * 128 + i * 16 + lr) * 64 + hk * 16;
        zA[i] = SWZ(z);
    }
#pragma unroll
    for (int j = 0; j < 4; ++j) {
        int z = (wn * 64 + j * 16 + lr) * 64 + hk * 16;
        zB[j] = SWZ(z);
    }

    // staging: linear LDS dest chunks q0,q1; global source inverse-swizzled
    const int q0 = tid, q1 = tid + 512;
    auto soff = [](int q) -> size_t {
        int z  = q * 16;
        int zs = SWZ(z);
        return (size_t)(zs >> 6) * IN_F + (size_t)((zs & 63) >> 1);
    };
    const ushort* gA0 = A + (size_t)mBase * IN_F + soff(q0);
    const ushort* gA1 = A + (size_t)mBase * IN_F + soff(q1);
    const ushort* gB0 = B + (size_t)nBase * IN_F + soff(q0);
    const ushort* gB1 = B + (size_t)nBase * IN_F + soff(q1);

    char* const bufs[4] = { smem, smem + 32768, smem + 65536, smem + 98304 };

    f32x4 acc[8][4] = {};

    // prologue: stage tiles 0,1,2 (12 loads/thread in flight)
#pragma unroll
    for (int t = 0; t < 3; ++t) {
        char* bb = bufs[t];
        GLDS(gA0 + (size_t)t * 32, bb + q0 * 16);
        GLDS(gA1 + (size_t)t * 32, bb + q1 * 16);
        GLDS(gB0 + (size_t)t * 32, bb + 16384 + q0 * 16);
        GLDS(gB1 + (size_t)t * 32, bb + 16384 + q1 * 16);
    }
    WAITV(8);        // tile 0 landed; tiles 1,2 still in flight
    BAR();
    FENCE();

    // One K-tile: 2 phases, each {ds_read frags | stage 2 gloads | BAR |
    // setprio(1) 16 MFMA setprio(0) | BAR}; counted vmcnt at tile end.
#define TILE(TT, POS, DOSTAGE, WN) do {                                         \
    char* bufA = bufs[(POS)];                                                   \
    char* bufB = bufA + 16384;                                                  \
    char* sb   = bufs[((POS) + 3) & 3];                                         \
    bf16x8 a0[4], bfr[4], a1[4];                                                \
    _Pragma("unroll")                                                           \
    for (int i = 0; i < 4; ++i) a0[i] = *(const bf16x8*)(bufA + zA[i]);         \
    _Pragma("unroll")                                                           \
    for (int j = 0; j < 4; ++j) bfr[j] = *(const bf16x8*)(bufB + zB[j]);        \
    if (DOSTAGE) {                                                              \
        GLDS(gA0 + (size_t)((TT) + 3) * 32, sb + q0 * 16);                      \
        GLDS(gA1 + (size_t)((TT) + 3) * 32, sb + q1 * 16);                      \
    }                                                                           \
    BAR();                                                                      \
    __builtin_amdgcn_s_setprio(1);                                              \
    _Pragma("unroll")                                                           \
    for (int i = 0; i < 4; ++i)                                                 \
        _Pragma("unroll")                                                       \
        for (int j = 0; j < 4; ++j)                                             \
            acc[i][j] = __builtin_amdgcn_mfma_f32_16x16x32_bf16(a0[i], bfr[j],  \
                                                                acc[i][j], 0, 0, 0); \
    __builtin_amdgcn_s_setprio(0);                                              \
    BAR();                                                                      \
    _Pragma("unroll")                                                           \
    for (int i = 0; i < 4; ++i) a1[i] = *(const bf16x8*)(bufA + zA[4 + i]);     \
    if (DOSTAGE) {                                                              \
        GLDS(gB0 + (size_t)((TT) + 3) * 32, sb + 16384 + q0 * 16);              \
        GLDS(gB1 + (size_t)((TT) + 3) * 32, sb + 16384 + q1 * 16);              \
    }                                                                           \
    BAR();                                                                      \
    __builtin_amdgcn_s_setprio(1);                                              \
    _Pragma("unroll")                                                           \
    for (int i = 0; i < 4; ++i)                                                 \
        _Pragma("unroll")                                                       \
        for (int j = 0; j < 4; ++j)                                             \
            acc[4 + i][j] = __builtin_amdgcn_mfma_f32_16x16x32_bf16(a1[i], bfr[j], \
                                                                    acc[4 + i][j], 0, 0, 0); \
    __builtin_amdgcn_s_setprio(0);                                              \
    WN;                                                                         \
    BAR();                                                                      \
    FENCE();                                                                    \
} while (0)

#pragma unroll 1
    for (int T0 = 0; T0 < NT - 4; T0 += 4) {   // tiles 0..123, always staging
        TILE(T0 + 0, 0, 1, WAITV(8));
        TILE(T0 + 1, 1, 1, WAITV(8));
        TILE(T0 + 2, 2, 1, WAITV(8));
        TILE(T0 + 3, 3, 1, WAITV(8));
    }
    // tail: tiles 124..127 — stage last tile, then drain 8 -> 4 -> 0
    TILE(NT - 4, 0, 1, WAITV(8));
    TILE(NT - 3, 1, 0, WAITV(4));
    TILE(NT - 2, 2, 0, WAITV(0));
    TILE(NT - 1, 3, 0, ((void)0));
#undef TILE

    // epilogue: C/D layout col = lane&15, row = (lane>>4)*4 + reg
#pragma unroll
    for (int i = 0; i < 8; ++i) {
        const int row = mBase + wm * 128 + i * 16 + hk * 4;
#pragma unroll
        for (int j = 0; j < 4; ++j) {
            const int col = nBase + wn * 64 + j * 16 + lr;
            const float bv = bias[col];
#pragma unroll
            for (int q = 0; q < 4; ++q)
                C[(size_t)(row + q) * OUT_F + col] = acc[i][j][q] + bv;
        }
    }
}

// ---- round-1 128^2 kernel kept as fallback (static 32KB LDS) -----------------
__global__ __launch_bounds__(256, 2) void k_gemm(const ushort* __restrict__ A,
                                                 const ushort* __restrict__ B,
                                                 const float* __restrict__ bias,
                                                 float* __restrict__ C) {
    __shared__ __align__(16) ushort lA[128 * 32];
    __shared__ __align__(16) ushort lB[128 * 32];
    const int tid  = threadIdx.x;
    const int lane = tid & 63;
    const int wave = tid >> 6;
    const int wm = wave >> 1, wn = wave & 1;
    const int mBase = blockIdx.y * 128, nBase = blockIdx.x * 128;
    const int lr = lane & 15, lk = (lane >> 4) * 8;
    f32x4 acc[4][4] = {};
    const int sr = tid >> 2, ss = (tid & 3) * 8;
    const ushort* gA0 = A + (size_t)(mBase + sr) * IN_F + ss;
    const ushort* gA1 = A + (size_t)(mBase + 64 + sr) * IN_F + ss;
    const ushort* gB0 = B + (size_t)(nBase + sr) * IN_F + ss;
    const ushort* gB1 = B + (size_t)(nBase + 64 + sr) * IN_F + ss;
    char* laByte = (char*)lA;
    char* lbByte = (char*)lB;
    for (int k0 = 0; k0 < IN_F; k0 += 32) {
        GLDS(gA0 + k0, laByte + tid * 16);
        GLDS(gA1 + k0, laByte + 4096 + tid * 16);
        GLDS(gB0 + k0, lbByte + tid * 16);
        GLDS(gB1 + k0, lbByte + 4096 + tid * 16);
        __syncthreads();
        bf16x8 af[4], bg[4];
#pragma unroll
        for (int i = 0; i < 4; ++i) af[i] = *(const bf16x8*)&lA[(wm * 64 + i * 16 + lr) * 32 + lk];
#pragma unroll
        for (int j = 0; j < 4; ++j) bg[j] = *(const bf16x8*)&lB[(wn * 64 + j * 16 + lr) * 32 + lk];
#pragma unroll
        for (int i = 0; i < 4; ++i)
#pragma unroll
            for (int j = 0; j < 4; ++j)
                acc[i][j] = __builtin_amdgcn_mfma_f32_16x16x32_bf16(af[i], bg[j], acc[i][j], 0, 0, 0);
        __syncthreads();
    }
#pragma unroll
    for (int i = 0; i < 4; ++i) {
        const int row = mBase + wm * 64 + i * 16 + (lane >> 4) * 4;
#pragma unroll
        for (int j = 0; j < 4; ++j) {
            const int col = nBase + wn * 64 + j * 16 + lr;
            const float bv = bias[col];
#pragma unroll
            for (int q = 0; q < 4; ++q)
                C[(size_t)(row + q) * OUT_F + col] = acc[i][j][q] + bv;
        }
    }
}

// ---- fp32 fallback if ws too small ------------------------------------------
__global__ __launch_bounds__(256) void k_fallback(const float* __restrict__ x,
                                                  const float* __restrict__ w1,
                                                  const float* __restrict__ w2,
                                                  const float* __restrict__ bias,
                                                  float* __restrict__ C) {
    __shared__ float sx[64][17];
    __shared__ float sw[64][17];
    const int tid = threadIdx.x;
    const int mb = blockIdx.y * 64, nb = blockIdx.x * 64;
    const int ty = tid >> 4, tx = tid & 15;
    float acc[4][4] = {};
    const int r = tid >> 2, s = (tid & 3) * 4;
    for (int k0 = 0; k0 < IN_F; k0 += 16) {
        float4 xv = *(const float4*)&x[(size_t)(mb + r) * IN_F + k0 + s];
        float4 a1 = *(const float4*)&w1[(size_t)(nb + r) * IN_F + k0 + s];
        float4 a2 = *(const float4*)&w2[(size_t)(nb + r) * IN_F + k0 + s];
        sx[r][s + 0] = xv.x; sx[r][s + 1] = xv.y; sx[r][s + 2] = xv.z; sx[r][s + 3] = xv.w;
        sw[r][s + 0] = tern(a1.x, a2.x); sw[r][s + 1] = tern(a1.y, a2.y);
        sw[r][s + 2] = tern(a1.z, a2.z); sw[r][s + 3] = tern(a1.w, a2.w);
        __syncthreads();
#pragma unroll
        for (int kk = 0; kk < 16; ++kk) {
            float av[4], bv[4];
#pragma unroll
            for (int i = 0; i < 4; ++i) av[i] = sx[ty * 4 + i][kk];
#pragma unroll
            for (int j = 0; j < 4; ++j) bv[j] = sw[tx * 4 + j][kk];
#pragma unroll
            for (int i = 0; i < 4; ++i)
#pragma unroll
                for (int j = 0; j < 4; ++j) acc[i][j] += av[i] * bv[j];
        }
        __syncthreads();
    }
#pragma unroll
    for (int i = 0; i < 4; ++i)
#pragma unroll
        for (int j = 0; j < 4; ++j)
            C[(size_t)(mb + ty * 4 + i) * OUT_F + nb + tx * 4 + j] = acc[i][j] + bias[nb + tx * 4 + j];
}

extern "C" void kernel_launch(void* const* d_in, const int* in_sizes, int n_in,
                              void* d_out, int out_size, void* d_ws, size_t ws_size,
                              hipStream_t stream) {
    const float* x    = (const float*)d_in[0];
    const float* w1   = (const float*)d_in[1];
    const float* w2   = (const float*)d_in[2];
    const float* bias = (const float*)d_in[3];
    float* out = (float*)d_out;

    const size_t need = ((size_t)TOKENS * IN_F + (size_t)OUT_F * IN_F) * sizeof(ushort);
    if (ws_size >= need) {
        ushort* xb = (ushort*)d_ws;
        ushort* wb = xb + (size_t)TOKENS * IN_F;
        k_xconv<<<1024, 256, 0, stream>>>((const float4*)x, xb, TOKENS * IN_F / 4);
        k_ternarize<<<2048, 256, 0, stream>>>((const float4*)w1, (const float4*)w2, wb,
                                              OUT_F * IN_F / 4);
        hipError_t e = hipFuncSetAttribute((const void*)k_gemm256,
                                           hipFuncAttributeMaxDynamicSharedMemorySize, 131072);
        if (e == hipSuccess) {
            k_gemm256<<<dim3(1024), 512, 131072, stream>>>(xb, wb, bias, out);
        } else {
            dim3 grid(OUT_F / 128, TOKENS / 128);
            k_gemm<<<grid, 256, 0, stream>>>(xb, wb, bias, out);
        }
    } else {
        dim3 grid(OUT_F / 64, TOKENS / 64);
        k_fallback<<<grid, 256, 0, stream>>>(x, w1, w2, bias, out);
    }
}